// Round 1
// 363.444 us; speedup vs baseline: 1.0458x; 1.0458x over previous
//
#include <hip/hip_runtime.h>
#include <cmath>

#define B_   2
#define S_   2048
#define H_   2304
#define NH_  8
#define HD_  256
#define NKV_ 4
#define WIN_ 512
#define QKVW 4096   // fused QKV output row width (8+4+4 heads * 256)

typedef unsigned short ushort_t;
typedef __attribute__((ext_vector_type(8))) short bf16x8;     // 8 bf16 = 4 VGPRs
typedef __attribute__((ext_vector_type(4))) float floatx4;

// round-to-nearest-even fp32 -> bf16
__device__ __forceinline__ unsigned short f2bf(float f) {
  unsigned u = __builtin_bit_cast(unsigned, f);
  u += 0x7fff + ((u >> 16) & 1);
  return (unsigned short)(u >> 16);
}
__device__ __forceinline__ float bf2f(ushort_t v) {
  unsigned u = (unsigned)v << 16;
  return __builtin_bit_cast(float, u);
}

// async global->LDS, 16 B per lane. LDS dest = wave-uniform base + lane*16.
__device__ __forceinline__ void gl2lds16(const void* g, void* l) {
  __builtin_amdgcn_global_load_lds(
      (const __attribute__((address_space(1))) unsigned int*)g,
      (__attribute__((address_space(3))) unsigned int*)l, 16, 0, 0);
}

// ---------------------------------------------------------------------------
// Elementwise fp32 -> bf16 cast (4 elems/thread).
// ---------------------------------------------------------------------------
__global__ void cast_bf16(const float* __restrict__ in, ushort_t* __restrict__ out) {
  const int i = blockIdx.x * 256 + threadIdx.x;
  float4 v = ((const float4*)in)[i];
  ushort4 o;
  o.x = f2bf(v.x); o.y = f2bf(v.y); o.z = f2bf(v.z); o.w = f2bf(v.w);
  ((ushort4*)out)[i] = o;
}

// ---------------------------------------------------------------------------
// W[K,N] fp32 -> Wt[N,K] bf16 (32x32 LDS tiles, 256 threads).
// ---------------------------------------------------------------------------
__global__ void transpose_cast(const float* __restrict__ W, ushort_t* __restrict__ Wt,
                               int K, int N) {
  __shared__ float t[32][33];
  const int lx = threadIdx.x & 31, ly = threadIdx.x >> 5;   // ly 0..7
  const int n0 = blockIdx.x * 32, k0 = blockIdx.y * 32;
#pragma unroll
  for (int i = 0; i < 4; ++i)
    t[ly + i * 8][lx] = W[(long long)(k0 + ly + i * 8) * N + n0 + lx];
  __syncthreads();
#pragma unroll
  for (int i = 0; i < 4; ++i)
    Wt[(long long)(n0 + ly + i * 8) * K + k0 + lx] = f2bf(t[lx][ly + i * 8]);
}

// ===========================================================================
// 256x256-tile 8-phase bf16 MFMA GEMM (T2+T3+T4+T5 template port).
//   C[M,N] = A[M,K] @ Bt[N,K]^T
// 512 threads = 8 waves (2 M x 4 N), per-wave 128x64 output (acc[8][4]),
// BK=64, double-buffered 128 KiB LDS (dynamic), global_load_lds width=16
// with chunk^(row&7) swizzle applied via pre-swizzled GLOBAL source
// (linear LDS dest), counted vmcnt(6) only at tile boundaries,
// raw s_barrier + lgkmcnt(0) + setprio(1) around each 16-MFMA phase.
//
// Per K-tile, 4 phases over C-quadrants (qm,qn); B-fragments are cached in
// registers across phases so each LDS region is read in exactly ONE phase:
//   ph1 (0,0): ds A-set0 (8xb128) + B-set0 (4xb128); stage A1(t+1)->other buf
//   ph2 (0,1): ds B-set1 (4xb128);                   stage A0(t+2)->this buf
//   ph3 (1,0): ds A-set1 (8xb128);                   stage B0(t+2)->this buf
//   ph4 (1,1): (all in regs);                        stage B1(t+2)->this buf
//              vmcnt(6) (=3 half-tiles in flight; vmcnt(0) before last tile)
// Region retirement: A0,B0 after ph1; B1 after ph2; A1 after ph3 — each
// staging lands in a region whose reads completed >=1 barrier earlier.
// ===========================================================================
#define LOAD_A(qm_) do { \
  _Pragma("unroll") for (int i_ = 0; i_ < 4; ++i_) { \
    const int row_ = wm + (qm_) * 64 + i_ * 16 + l15; \
    _Pragma("unroll") for (int kk_ = 0; kk_ < 2; ++kk_) \
      a[i_][kk_] = *(const bf16x8*)&ldsA[row_ * 64 + (((kk_ * 4 + lq) ^ (l15 & 7)) * 8)]; \
  } \
} while (0)

#define LOAD_B(qn_) do { \
  _Pragma("unroll") for (int j_ = 0; j_ < 2; ++j_) { \
    const int row_ = wn + (qn_) * 32 + j_ * 16 + l15; \
    _Pragma("unroll") for (int kk_ = 0; kk_ < 2; ++kk_) \
      b[qn_][j_][kk_] = *(const bf16x8*)&ldsB[row_ * 64 + (((kk_ * 4 + lq) ^ (l15 & 7)) * 8)]; \
  } \
} while (0)

#define MFMA_QUAD(qm_, qn_) do { \
  _Pragma("unroll") for (int kk_ = 0; kk_ < 2; ++kk_) \
  _Pragma("unroll") for (int i_ = 0; i_ < 4; ++i_) \
  _Pragma("unroll") for (int j_ = 0; j_ < 2; ++j_) \
    acc[(qm_) * 4 + i_][(qn_) * 2 + j_] = __builtin_amdgcn_mfma_f32_16x16x32_bf16( \
        a[i_][kk_], b[qn_][j_][kk_], acc[(qm_) * 4 + i_][(qn_) * 2 + j_], 0, 0, 0); \
} while (0)

// stage one 128-row x 64-col half-tile (16 KB): 2 x global_load_lds per lane.
// A-set qm: rows {qm*64..+63} U {128+qm*64..+63} of the 256-row tile.
#define STAGE_A(dst_, gsrc_, t_, qm_) do { \
  _Pragma("unroll") for (int jj_ = 0; jj_ < 2; ++jj_) { \
    const int g_ = w * 2 + jj_; \
    const int tr0_ = ((g_ >> 3) * 128) + (qm_) * 64 + (g_ & 7) * 8; \
    gl2lds16(gsrc_ + (size_t)tr0_ * K + (size_t)(t_) * 64 + laneOff, dst_ + tr0_ * 64); \
  } \
} while (0)

// B-set qn: rows {q*64 + qn*32 .. +31} for q=0..3.
#define STAGE_B(dst_, gsrc_, t_, qn_) do { \
  _Pragma("unroll") for (int jj_ = 0; jj_ < 2; ++jj_) { \
    const int g_ = w * 2 + jj_; \
    const int tr0_ = ((g_ >> 2) * 64) + (qn_) * 32 + (g_ & 3) * 8; \
    gl2lds16(gsrc_ + (size_t)tr0_ * K + (size_t)(t_) * 64 + laneOff, dst_ + tr0_ * 64); \
  } \
} while (0)

template <bool OUT_BF16>
__launch_bounds__(512)
__global__ void gemm_8ph(const ushort_t* __restrict__ A,   // [M,K] bf16
                         const ushort_t* __restrict__ Bt,  // [N,K] bf16
                         void* __restrict__ Cv, int M, int N, int K) {
  extern __shared__ __attribute__((aligned(128))) ushort_t smem[];
  const int tid = threadIdx.x, lane = tid & 63, w = tid >> 6;   // w 0..7
  const int wm = (w >> 2) * 128, wn = (w & 3) * 64;
  const int l15 = lane & 15, lq = lane >> 4;
  const int bm = blockIdx.y * 256, bn = blockIdx.x * 256;
  const int NT = K >> 6;

  const ushort_t* Ab = A + (size_t)bm * K;
  const ushort_t* Bb = Bt + (size_t)bn * K;
  // per-lane source offset: row += lane>>3, chunk = (lane&7)^(lane>>3) (swizzle)
  const size_t laneOff = (size_t)(lane >> 3) * K + (size_t)(((lane & 7) ^ (lane >> 3)) * 8);

  ushort_t* A0s = smem;             // buf0 A  (256x64)
  ushort_t* B0s = smem + 16384;     // buf0 B
  ushort_t* A1s = smem + 32768;     // buf1 A
  ushort_t* B1s = smem + 49152;     // buf1 B

  floatx4 acc[8][4] = {};

  // ---- prologue: tile0 fully + tile1 first 3 half-tiles (steady state = 3 in flight)
  STAGE_A(A0s, Ab, 0, 0);
  STAGE_B(B0s, Bb, 0, 0);
  STAGE_B(B0s, Bb, 0, 1);
  STAGE_A(A0s, Ab, 0, 1);
  asm volatile("s_waitcnt vmcnt(4)" ::: "memory");
  if (NT > 1) {
    STAGE_A(A1s, Ab, 1, 0);
    STAGE_B(B1s, Bb, 1, 0);
    STAGE_B(B1s, Bb, 1, 1);
    asm volatile("s_waitcnt vmcnt(6)" ::: "memory");
  } else {
    asm volatile("s_waitcnt vmcnt(0)" ::: "memory");
  }
  __builtin_amdgcn_s_barrier();

  for (int t = 0; t < NT; ++t) {
    ushort_t* ldsA  = (t & 1) ? A1s : A0s;
    ushort_t* ldsB  = (t & 1) ? B1s : B0s;
    ushort_t* ldsAo = (t & 1) ? A0s : A1s;   // other buffer's A (tile t+1)

    bf16x8 a[4][2], b[2][2][2];

    // ---- phase 1: quadrant (0,0)
    LOAD_A(0);
    LOAD_B(0);
    if (t + 1 < NT) STAGE_A(ldsAo, Ab, t + 1, 1);
    __builtin_amdgcn_s_barrier();
    asm volatile("s_waitcnt lgkmcnt(0)" ::: "memory");
    __builtin_amdgcn_s_setprio(1);
    MFMA_QUAD(0, 0);
    __builtin_amdgcn_s_setprio(0);
    __builtin_amdgcn_s_barrier();

    // ---- phase 2: quadrant (0,1)
    LOAD_B(1);
    if (t + 2 < NT) STAGE_A(ldsA, Ab, t + 2, 0);
    __builtin_amdgcn_s_barrier();
    asm volatile("s_waitcnt lgkmcnt(0)" ::: "memory");
    __builtin_amdgcn_s_setprio(1);
    MFMA_QUAD(0, 1);
    __builtin_amdgcn_s_setprio(0);
    __builtin_amdgcn_s_barrier();

    // ---- phase 3: quadrant (1,0)  (reuses b[0] from registers)
    LOAD_A(1);
    if (t + 2 < NT) STAGE_B(ldsB, Bb, t + 2, 0);
    __builtin_amdgcn_s_barrier();
    asm volatile("s_waitcnt lgkmcnt(0)" ::: "memory");
    __builtin_amdgcn_s_setprio(1);
    MFMA_QUAD(1, 0);
    __builtin_amdgcn_s_setprio(0);
    __builtin_amdgcn_s_barrier();

    // ---- phase 4: quadrant (1,1)  (all operands in registers)
    if (t + 2 < NT) STAGE_B(ldsB, Bb, t + 2, 1);
    __builtin_amdgcn_s_barrier();
    __builtin_amdgcn_s_setprio(1);
    MFMA_QUAD(1, 1);
    __builtin_amdgcn_s_setprio(0);
    if (t < NT - 1) {                        // tile-boundary counted drain
      if (t == NT - 2) asm volatile("s_waitcnt vmcnt(0)" ::: "memory");
      else             asm volatile("s_waitcnt vmcnt(6)" ::: "memory");
    }
    __builtin_amdgcn_s_barrier();
  }

  // ---- epilogue: C write (C/D layout: row = lq*4+rr, col = l15 per 16x16 frag)
  const int r0 = lq * 4;
#pragma unroll
  for (int mf = 0; mf < 8; ++mf)
#pragma unroll
    for (int nf = 0; nf < 4; ++nf) {
      const long long base = (long long)(bm + wm + mf * 16 + r0) * N + bn + wn + nf * 16 + l15;
      if (OUT_BF16) {
        ushort_t* Cp = (ushort_t*)Cv + base;
#pragma unroll
        for (int rr = 0; rr < 4; ++rr) Cp[(long long)rr * N] = f2bf(acc[mf][nf][rr]);
      } else {
        float* Cp = (float*)Cv + base;
#pragma unroll
        for (int rr = 0; rr < 4; ++rr) Cp[(long long)rr * N] = acc[mf][nf][rr];
      }
    }
}

#undef LOAD_A
#undef LOAD_B
#undef MFMA_QUAD
#undef STAGE_A
#undef STAGE_B

// ---------------------------------------------------------------------------
// Fallback 128x128 GEMM (register-double-buffered) — used only if the
// dynamic-LDS attribute is unavailable.
// ---------------------------------------------------------------------------
template <bool OUT_BF16>
__launch_bounds__(256)
__global__ void gemm_bt(const ushort_t* __restrict__ A,   // [M,K] bf16
                        const ushort_t* __restrict__ Bt,  // [N,K] bf16
                        void* __restrict__ Cv, int M, int N, int K) {
  __shared__ ushort_t As[128 * 64];
  __shared__ ushort_t Bs[128 * 64];
  const int tid = threadIdx.x, lane = tid & 63, wid = tid >> 6;
  const int bm = blockIdx.y * 128, bn = blockIdx.x * 128;
  const int wm = (wid >> 1) * 64, wn = (wid & 1) * 64;

  floatx4 acc[4][4] = {};

  const int r  = tid >> 1;
  const int cp = (tid & 1) * 4;
  const int wkey = r & 7;
  const ushort_t* Ap = A  + (long long)(bm + r) * K + cp * 8;
  const ushort_t* Bp = Bt + (long long)(bn + r) * K + cp * 8;
  ushort_t* Aw = &As[r * 64];
  ushort_t* Bw = &Bs[r * 64];

  const int l15 = lane & 15, lq = lane >> 4;
  const int rkey = l15 & 7;

  bf16x8 ar[4], br[4];
#pragma unroll
  for (int i = 0; i < 4; ++i) {
    ar[i] = *(const bf16x8*)(Ap + i * 8);
    br[i] = *(const bf16x8*)(Bp + i * 8);
  }

  for (int k0 = 0; k0 < K; k0 += 64) {
    __syncthreads();
#pragma unroll
    for (int i = 0; i < 4; ++i) {
      *(bf16x8*)&Aw[((cp + i) ^ wkey) * 8] = ar[i];
      *(bf16x8*)&Bw[((cp + i) ^ wkey) * 8] = br[i];
    }
    __syncthreads();

    if (k0 + 64 < K) {
      const int kn = k0 + 64;
#pragma unroll
      for (int i = 0; i < 4; ++i) {
        ar[i] = *(const bf16x8*)(Ap + kn + i * 8);
        br[i] = *(const bf16x8*)(Bp + kn + i * 8);
      }
    }

#pragma unroll
    for (int kk = 0; kk < 2; ++kk) {
      bf16x8 af[4], bfr[4];
#pragma unroll
      for (int i = 0; i < 4; ++i) {
        af[i]  = *(const bf16x8*)&As[(wm + i * 16 + l15) * 64 + ((kk * 4 + lq) ^ rkey) * 8];
        bfr[i] = *(const bf16x8*)&Bs[(wn + i * 16 + l15) * 64 + ((kk * 4 + lq) ^ rkey) * 8];
      }
#pragma unroll
      for (int i = 0; i < 4; ++i)
#pragma unroll
        for (int j = 0; j < 4; ++j)
          acc[i][j] = __builtin_amdgcn_mfma_f32_16x16x32_bf16(af[i], bfr[j], acc[i][j], 0, 0, 0);
    }
  }

  const int r0 = lq * 4, c0 = l15;
#pragma unroll
  for (int i = 0; i < 4; ++i)
#pragma unroll
    for (int j = 0; j < 4; ++j) {
      const long long base = (long long)(bm + wm + i * 16 + r0) * N + bn + wn + j * 16 + c0;
      if (OUT_BF16) {
        ushort_t* Cp = (ushort_t*)Cv + base;
#pragma unroll
        for (int rr = 0; rr < 4; ++rr) Cp[(long long)rr * N] = f2bf(acc[i][j][rr]);
      } else {
        float* Cp = (float*)Cv + base;
#pragma unroll
        for (int rr = 0; rr < 4; ++rr) Cp[(long long)rr * N] = acc[i][j][rr];
      }
    }
}

// ---------------------------------------------------------------------------
// In-place RoPE on QKV16 [B*S][4096] bf16 (Q cols 0..2047, K cols 2048..3071).
// Also folds the 1/16 attention scale into Q. V region untouched.
// ---------------------------------------------------------------------------
__global__ void rope_inplace(ushort_t* __restrict__ QKV16, const int* __restrict__ pos) {
  const int bs  = blockIdx.x;
  const int gid = blockIdx.y * 256 + threadIdx.x;
  const int head = gid >> 7;          // 0..11
  const int d    = gid & 127;
  const float pp   = (float)pos[bs];
  const float invf = __expf(-(float)d * (9.210340371976184f / 128.0f));
  const float ang  = pp * invf;
  const float cc = cosf(ang), sn = sinf(ang);
  ushort_t* base = QKV16 + (size_t)bs * QKVW + head * HD_;
  const float x1 = bf2f(base[d]);
  const float x2 = bf2f(base[d + 128]);
  float o1 = x1 * cc - x2 * sn;
  float o2 = x2 * cc + x1 * sn;
  if (head < NH_) { o1 *= 0.0625f; o2 *= 0.0625f; }   // fold 1/sqrt(256) into Q
  base[d]       = f2bf(o1);
  base[d + 128] = f2bf(o2);
}

// ---------------------------------------------------------------------------
// V transpose: QKV16 V region -> Vt16 [B][NKV][256][S] bf16.
// ---------------------------------------------------------------------------
__global__ void v_prep(const ushort_t* __restrict__ QKV16, ushort_t* __restrict__ Vt16) {
  __shared__ ushort_t tile[32][33];
  const int k0 = blockIdx.x * 32, d0 = blockIdx.y * 32;
  const int b = blockIdx.z >> 2, hk = blockIdx.z & 3;
  const int lx = threadIdx.x & 31, ly = threadIdx.x >> 5;
#pragma unroll
  for (int i = 0; i < 4; ++i)
    tile[ly + 8 * i][lx] =
        QKV16[(size_t)(b * S_ + k0 + ly + 8 * i) * QKVW + 3072 + hk * HD_ + d0 + lx];
  __syncthreads();
#pragma unroll
  for (int i = 0; i < 4; ++i)
    Vt16[((size_t)(b * NKV_ + hk) * HD_ + d0 + ly + 8 * i) * S_ + k0 + lx] =
        tile[lx][ly + 8 * i];
}

// ---------------------------------------------------------------------------
// MFMA flash attention, head-PAIR per block (both heads share hk's K/V).
// 512 threads = 8 waves: waves 0-3 -> head 2*hp, waves 4-7 -> head 2*hp+1.
// ---------------------------------------------------------------------------
__launch_bounds__(512)
__global__ void attn_mfma(const ushort_t* __restrict__ QKV16,  // [B*S][4096]
                          const ushort_t* __restrict__ Vt16,   // [B][NKV][256][S]
                          ushort_t* __restrict__ AOb) {        // [B][S][NH][256]
  __shared__ ushort_t Ks[32 * 256];    // [key][dim], chunk-swizzled
  __shared__ ushort_t Vts[256 * 32];   // [dim][key], chunk-swizzled
  __shared__ ushort_t Ps[8][16 * 32];  // per-wave P [q][key], chunk-swizzled
  __shared__ float rsb[8][16];

  const int lane = threadIdx.x & 63, w = threadIdx.x >> 6;   // w 0..7
  const int l15 = lane & 15, lq = lane >> 4;
  const int qb = blockIdx.x * 64;
  const int hp = blockIdx.y, b = blockIdx.z;                 // hp = hk
  const int h  = hp * 2 + (w >> 2);
  const int hw = w & 3;                                      // wave-in-head

  const ushort_t* Qh = QKV16 + (size_t)b * S_ * QKVW + h * HD_;
  const ushort_t* Kh = QKV16 + (size_t)b * S_ * QKVW + 2048 + hp * HD_;
  const ushort_t* Vh = Vt16 + ((size_t)(b * NKV_ + hp) * HD_) * S_;

  const int qw = qb + hw * 16;   // wave's first query

  bf16x8 afq[8];
  {
    const ushort_t* qr = Qh + (size_t)(qw + l15) * QKVW + lq * 8;
#pragma unroll
    for (int kd = 0; kd < 8; ++kd) afq[kd] = *(const bf16x8*)(qr + kd * 32);
  }

  floatx4 acc[16] = {};
  float rs[4] = {0.f, 0.f, 0.f, 0.f};

  int kb0 = qb - (WIN_ - 1);
  if (kb0 < 0) kb0 = 0;
  kb0 &= ~31;

  const int ksp = lane & 31, ksr = lane >> 5;
  const int vsp = lane & 3,  vsr = lane >> 2;

  for (int kb = kb0; kb < qb + 64; kb += 32) {
    __syncthreads();
#pragma unroll
    for (int i = 0; i < 2; ++i) {
      const int kl = w * 4 + 2 * i + ksr;
      gl2lds16(Kh + (size_t)(kb + kl) * QKVW + (ksp ^ (kl & 31)) * 8,
               &Ks[(w * 4 + 2 * i) * 256]);
    }
#pragma unroll
    for (int i = 0; i < 2; ++i) {
      const int dl = w * 32 + 16 * i + vsr;
      gl2lds16(Vh + (size_t)dl * S_ + kb + (vsp ^ ((dl >> 1) & 3)) * 8,
               &Vts[(w * 32 + 16 * i) * 32]);
    }
    __syncthreads();

    if (kb <= qw + 15 && kb + 31 >= qw - (WIN_ - 1)) {
      ushort_t* Pw = Ps[w];
#pragma unroll
      for (int kt = 0; kt < 2; ++kt) {
        floatx4 sacc = {};
        const int keyl = kt * 16 + l15;
        const int krow = keyl * 256;
        const int ksw = keyl & 31;
#pragma unroll
        for (int kd = 0; kd < 8; ++kd) {
          bf16x8 bk = *(const bf16x8*)&Ks[krow + ((kd * 4 + lq) ^ ksw) * 8];
          sacc = __builtin_amdgcn_mfma_f32_16x16x32_bf16(afq[kd], bk, sacc, 0, 0, 0);
        }
        const int keyg = kb + keyl;
#pragma unroll
        for (int rr = 0; rr < 4; ++rr) {
          const int qg = qw + lq * 4 + rr;
          const float t = __expf(sacc[rr] * 0.04f);
          const float L = 50.f - __fdividef(100.f, t + 1.f);
          float p = __expf(L);
          p = (keyg <= qg && keyg >= qg - (WIN_ - 1)) ? p : 0.f;
          rs[rr] += p;
          const int ql = lq * 4 + rr;
          const int ch = kt * 2 + (l15 >> 3);
          Pw[ql * 32 + ((ch ^ ((ql >> 1) & 3)) * 8) + (l15 & 7)] = f2bf(p);
        }
      }
      asm volatile("s_waitcnt lgkmcnt(0)" ::: "memory");

      const bf16x8 bp = *(const bf16x8*)&Pw[l15 * 32 + ((lq ^ ((l15 >> 1) & 3)) * 8)];
      const int vsw = (l15 >> 1) & 3;
#pragma unroll
      for (int t = 0; t < 16; ++t) {
        bf16x8 av = *(const bf16x8*)&Vts[(t * 16 + l15) * 32 + ((lq ^ vsw) * 8)];
        acc[t] = __builtin_amdgcn_mfma_f32_16x16x32_bf16(av, bp, acc[t], 0, 0, 0);
      }
    }
  }

#pragma unroll
  for (int rr = 0; rr < 4; ++rr) {
    rs[rr] += __shfl_xor(rs[rr], 1, 64);
    rs[rr] += __shfl_xor(rs[rr], 2, 64);
    rs[rr] += __shfl_xor(rs[rr], 4, 64);
    rs[rr] += __shfl_xor(rs[rr], 8, 64);
  }
  if (l15 == 0) {
#pragma unroll
    for (int rr = 0; rr < 4; ++rr) rsb[w][lq * 4 + rr] = rs[rr];
  }
  asm volatile("s_waitcnt lgkmcnt(0)" ::: "memory");
  __builtin_amdgcn_wave_barrier();
  const float inv = 1.0f / rsb[w][l15];

  const size_t ob = ((size_t)(b * S_ + qw + l15) * NH_ + h) * HD_;
#pragma unroll
  for (int t = 0; t < 16; ++t) {
    ushort4 o;
    o.x = f2bf(acc[t][0] * inv);
    o.y = f2bf(acc[t][1] * inv);
    o.z = f2bf(acc[t][2] * inv);
    o.w = f2bf(acc[t][3] * inv);
    *(ushort4*)&AOb[ob + t * 16 + lq * 4] = o;
  }
}

// ---------------------------------------------------------------------------
extern "C" void kernel_launch(void* const* d_in, const int* in_sizes, int n_in,
                              void* d_out, int out_size, void* d_ws, size_t ws_size,
                              hipStream_t stream) {
  const float* X   = (const float*)d_in[0];
  const int*   pos = (const int*)d_in[2];
  const float* Wq  = (const float*)d_in[3];   // [2304, 2048]
  const float* Wk  = (const float*)d_in[4];   // [2304, 1024]
  const float* Wv  = (const float*)d_in[5];   // [2304, 1024]
  const float* Wo  = (const float*)d_in[6];   // [2048, 2304]
  float* out = (float*)d_out;

  const int M  = B_ * S_;        // 4096
  const int NQ = NH_ * HD_;      // 2048
  const int NK = NKV_ * HD_;     // 1024

  char* w = (char*)d_ws;
  ushort_t* QKV16 = (ushort_t*)w;  w += (size_t)M * QKVW * 2;          // 32 MB
  ushort_t* Xb    = (ushort_t*)w;  w += (size_t)M * H_ * 2;            // 18 MB
  ushort_t* Wqkvt = (ushort_t*)w;  w += (size_t)QKVW * H_ * 2;         // 18 MB
  ushort_t* Wot   = (ushort_t*)w;  w += (size_t)H_ * NQ * 2;           // 9.4 MB
  ushort_t* Vt16  = (ushort_t*)w;  w += (size_t)B_ * NKV_ * S_ * HD_ * 2;  // 8 MB
  ushort_t* AOb   = (ushort_t*)w;  w += (size_t)M * NQ * 2;            // 16 MB

  // opt-in to 128 KiB dynamic LDS for the 8-phase GEMM (host-side, capture-safe)
  static bool g_init = false, g_8ph_ok = false;
  if (!g_init) {
    hipError_t e1 = hipFuncSetAttribute(
        reinterpret_cast<const void*>(&gemm_8ph<true>),
        hipFuncAttributeMaxDynamicSharedMemorySize, 131072);
    hipError_t e2 = hipFuncSetAttribute(
        reinterpret_cast<const void*>(&gemm_8ph<false>),
        hipFuncAttributeMaxDynamicSharedMemorySize, 131072);
    g_8ph_ok = (e1 == hipSuccess && e2 == hipSuccess);
    g_init = true;
  }

  dim3 blk(256);

  cast_bf16<<<(M * H_) / 1024, blk, 0, stream>>>(X, Xb);
  // concatenated transposed QKV weights: rows [0,2048)=Wq^T, [2048,3072)=Wk^T, [3072,4096)=Wv^T
  transpose_cast<<<dim3(NQ / 32, H_ / 32), blk, 0, stream>>>(Wq, Wqkvt, H_, NQ);
  transpose_cast<<<dim3(NK / 32, H_ / 32), blk, 0, stream>>>(Wk, Wqkvt + (size_t)2048 * H_, H_, NK);
  transpose_cast<<<dim3(NK / 32, H_ / 32), blk, 0, stream>>>(Wv, Wqkvt + (size_t)3072 * H_, H_, NK);
  transpose_cast<<<dim3(H_ / 32, NQ / 32), blk, 0, stream>>>(Wo, Wot, NQ, H_);

  // fused QKV projection, bf16 out (K=2304: 36 K-tiles)
  if (g_8ph_ok) {
    gemm_8ph<true><<<dim3(QKVW / 256, M / 256), dim3(512), 131072, stream>>>(
        Xb, Wqkvt, QKV16, M, QKVW, H_);
  } else {
    gemm_bt<true><<<dim3(QKVW / 128, M / 128), blk, 0, stream>>>(Xb, Wqkvt, QKV16, M, QKVW, H_);
  }

  rope_inplace<<<dim3(M, 6), blk, 0, stream>>>(QKV16, pos);
  v_prep<<<dim3(S_ / 32, HD_ / 32, B_ * NKV_), blk, 0, stream>>>(QKV16, Vt16);

  // attention: head-pair per block, 512 threads
  attn_mfma<<<dim3(S_ / 64, NKV_, B_), dim3(512), 0, stream>>>(QKV16, Vt16, AOb);

  // output projection, fp32 out (K=2048: 32 K-tiles; N=2304 -> 9 column tiles)
  if (g_8ph_ok) {
    gemm_8ph<false><<<dim3(H_ / 256, M / 256), dim3(512), 131072, stream>>>(
        AOb, Wot, out, M, H_, NQ);
  } else {
    gemm_bt<false><<<dim3(H_ / 128, M / 128), blk, 0, stream>>>(AOb, Wot, out, M, H_, NQ);
  }
}

// Round 2
// 357.346 us; speedup vs baseline: 1.0637x; 1.0171x over previous
//
#include <hip/hip_runtime.h>
#include <cmath>

#define B_   2
#define S_   2048
#define H_   2304
#define NH_  8
#define HD_  256
#define NKV_ 4
#define WIN_ 512
#define QKVW 4096   // fused QKV output row width (8+4+4 heads * 256)

typedef unsigned short ushort_t;
typedef __attribute__((ext_vector_type(8))) short bf16x8;     // 8 bf16 = 4 VGPRs
typedef __attribute__((ext_vector_type(4))) float floatx4;

// round-to-nearest-even fp32 -> bf16
__device__ __forceinline__ unsigned short f2bf(float f) {
  unsigned u = __builtin_bit_cast(unsigned, f);
  u += 0x7fff + ((u >> 16) & 1);
  return (unsigned short)(u >> 16);
}
__device__ __forceinline__ float bf2f(ushort_t v) {
  unsigned u = (unsigned)v << 16;
  return __builtin_bit_cast(float, u);
}

// async global->LDS, 16 B per lane. LDS dest = wave-uniform base + lane*16.
__device__ __forceinline__ void gl2lds16(const void* g, void* l) {
  __builtin_amdgcn_global_load_lds(
      (const __attribute__((address_space(1))) unsigned int*)g,
      (__attribute__((address_space(3))) unsigned int*)l, 16, 0, 0);
}

// ---------------------------------------------------------------------------
// Elementwise fp32 -> bf16 cast (4 elems/thread).
// ---------------------------------------------------------------------------
__global__ void cast_bf16(const float* __restrict__ in, ushort_t* __restrict__ out) {
  const int i = blockIdx.x * 256 + threadIdx.x;
  float4 v = ((const float4*)in)[i];
  ushort4 o;
  o.x = f2bf(v.x); o.y = f2bf(v.y); o.z = f2bf(v.z); o.w = f2bf(v.w);
  ((ushort4*)out)[i] = o;
}

// ---------------------------------------------------------------------------
// W[K,N] fp32 -> Wt[N,K] bf16 (32x32 LDS tiles, 256 threads).
// ---------------------------------------------------------------------------
__global__ void transpose_cast(const float* __restrict__ W, ushort_t* __restrict__ Wt,
                               int K, int N) {
  __shared__ float t[32][33];
  const int lx = threadIdx.x & 31, ly = threadIdx.x >> 5;   // ly 0..7
  const int n0 = blockIdx.x * 32, k0 = blockIdx.y * 32;
#pragma unroll
  for (int i = 0; i < 4; ++i)
    t[ly + i * 8][lx] = W[(long long)(k0 + ly + i * 8) * N + n0 + lx];
  __syncthreads();
#pragma unroll
  for (int i = 0; i < 4; ++i)
    Wt[(long long)(n0 + ly + i * 8) * K + k0 + lx] = f2bf(t[lx][ly + i * 8]);
}

// ===========================================================================
// 256x256-tile pipelined-phase bf16 MFMA GEMM:  C[M,N] = A[M,K] @ Bt[N,K]^T
// 512 threads = 8 waves (2M x 4N), per-wave 128x64 (acc[8][4]), BK=64,
// double-buffered 128 KiB dynamic LDS, global_load_lds width=16 with
// chunk^(row&7) swizzle via pre-swizzled GLOBAL source (linear LDS dest).
//
// KEY SCHEDULE (v2): ds_reads for phase p+1 are issued AFTER phase p's
// 16-MFMA cluster (sched_barrier-pinned), so the LDS drain overlaps the
// MFMA pipe; each phase's lgkmcnt(0) is then nearly satisfied. Gray-code
// quadrant order q00->q01->q11->q10 keeps per-phase new-operand sets small
// (B1:4, A1:8, -, A0+B0(t+1):12) with B0 held live -> frag regs stay 64
// VGPR (2 waves/SIMD preserved). 4 barriers/K-tile (was 8).
//
// Staging (unchanged mapping): ph1: A1(t+1)->other buf; ph2: A0(t+2);
// ph3: B0(t+2); ph4: B1(t+2). Tile-boundary wait moved to ph3-end and
// deepened to vmcnt(4): outstanding there (issue order) =
//   [A0,B0,B1](t+1) 6 + A1(t+1) 2 + A0(t+2) 2 + B0(t+2) 2 = 12;
// vmcnt(4) drains the 8 oldest = ALL of tile t+1 (needed because ph4 reads
// t+1's A0/B0 and ph1/ph2 of t+1 read B1/A1). vmcnt(0) at t==NT-2.
// WAR safety: each region's reads are lgkm-complete >=1 full barrier
// before its overwriting stage (checked per region).
// ===========================================================================
#define LDA_FROM(base_, qm_) do { \
  _Pragma("unroll") for (int i_ = 0; i_ < 4; ++i_) { \
    const int row_ = wm + (qm_) * 64 + i_ * 16 + l15; \
    _Pragma("unroll") for (int kk_ = 0; kk_ < 2; ++kk_) \
      aR[i_][kk_] = *(const bf16x8*)&(base_)[row_ * 64 + (((kk_ * 4 + lq) ^ (l15 & 7)) * 8)]; \
  } \
} while (0)

#define LDB_FROM(base_, dst_, qn_) do { \
  _Pragma("unroll") for (int j_ = 0; j_ < 2; ++j_) { \
    const int row_ = wn + (qn_) * 32 + j_ * 16 + l15; \
    _Pragma("unroll") for (int kk_ = 0; kk_ < 2; ++kk_) \
      dst_[j_][kk_] = *(const bf16x8*)&(base_)[row_ * 64 + (((kk_ * 4 + lq) ^ (l15 & 7)) * 8)]; \
  } \
} while (0)

#define MFMA_QUAD(qm_, qn_, breg_) do { \
  _Pragma("unroll") for (int kk_ = 0; kk_ < 2; ++kk_) \
  _Pragma("unroll") for (int i_ = 0; i_ < 4; ++i_) \
  _Pragma("unroll") for (int j_ = 0; j_ < 2; ++j_) \
    acc[(qm_) * 4 + i_][(qn_) * 2 + j_] = __builtin_amdgcn_mfma_f32_16x16x32_bf16( \
        aR[i_][kk_], breg_[j_][kk_], acc[(qm_) * 4 + i_][(qn_) * 2 + j_], 0, 0, 0); \
} while (0)

// stage one 128-row x 64-col half-tile (16 KB): 2 x global_load_lds per lane.
#define STAGE_A(dst_, gsrc_, t_, qm_) do { \
  _Pragma("unroll") for (int jj_ = 0; jj_ < 2; ++jj_) { \
    const int g_ = w * 2 + jj_; \
    const int tr0_ = ((g_ >> 3) * 128) + (qm_) * 64 + (g_ & 7) * 8; \
    gl2lds16(gsrc_ + (size_t)tr0_ * K + (size_t)(t_) * 64 + laneOff, dst_ + tr0_ * 64); \
  } \
} while (0)

#define STAGE_B(dst_, gsrc_, t_, qn_) do { \
  _Pragma("unroll") for (int jj_ = 0; jj_ < 2; ++jj_) { \
    const int g_ = w * 2 + jj_; \
    const int tr0_ = ((g_ >> 2) * 64) + (qn_) * 32 + (g_ & 3) * 8; \
    gl2lds16(gsrc_ + (size_t)tr0_ * K + (size_t)(t_) * 64 + laneOff, dst_ + tr0_ * 64); \
  } \
} while (0)

#define SB0() __builtin_amdgcn_sched_barrier(0)
#define LGKM0() do { asm volatile("s_waitcnt lgkmcnt(0)" ::: "memory"); SB0(); } while (0)

template <bool OUT_BF16>
__launch_bounds__(512)
__global__ void gemm_8ph(const ushort_t* __restrict__ A,   // [M,K] bf16
                         const ushort_t* __restrict__ Bt,  // [N,K] bf16
                         void* __restrict__ Cv, int M, int N, int K) {
  extern __shared__ __attribute__((aligned(128))) ushort_t smem[];
  const int tid = threadIdx.x, lane = tid & 63, w = tid >> 6;   // w 0..7
  const int wm = (w >> 2) * 128, wn = (w & 3) * 64;
  const int l15 = lane & 15, lq = lane >> 4;

  // T1: XCD-aware swizzle of the linear block id (grid %8 == 0 for both GEMMs)
  const int nwg  = gridDim.x * gridDim.y;
  const int orig = blockIdx.y * gridDim.x + blockIdx.x;
  const int cpx  = nwg >> 3;
  const int swz  = (orig & 7) * cpx + (orig >> 3);
  const int bx   = swz % gridDim.x, by = swz / gridDim.x;
  const int bm = by * 256, bn = bx * 256;
  const int NT = K >> 6;

  const ushort_t* Ab = A + (size_t)bm * K;
  const ushort_t* Bb = Bt + (size_t)bn * K;
  // per-lane source offset: row += lane>>3, chunk = (lane&7)^(lane>>3) (swizzle)
  const size_t laneOff = (size_t)(lane >> 3) * K + (size_t)(((lane & 7) ^ (lane >> 3)) * 8);

  ushort_t* A0s = smem;             // buf0 A  (256x64)
  ushort_t* B0s = smem + 16384;     // buf0 B
  ushort_t* A1s = smem + 32768;     // buf1 A
  ushort_t* B1s = smem + 49152;     // buf1 B

  floatx4 acc[8][4] = {};
  bf16x8 aR[4][2], b0[2][2], b1[2][2];

  // ---- prologue: stage tile0 fully + tile1's first 3 half-tiles
  STAGE_A(A0s, Ab, 0, 0);
  STAGE_B(B0s, Bb, 0, 0);
  STAGE_B(B0s, Bb, 0, 1);
  STAGE_A(A0s, Ab, 0, 1);
  if (NT > 1) {
    STAGE_A(A1s, Ab, 1, 0);
    STAGE_B(B1s, Bb, 1, 0);
    STAGE_B(B1s, Bb, 1, 1);
    asm volatile("s_waitcnt vmcnt(6)" ::: "memory");   // tile0 complete
  } else {
    asm volatile("s_waitcnt vmcnt(0)" ::: "memory");
  }
  __builtin_amdgcn_s_barrier();
  // initial operand reads for t=0 phase 1 (q00)
  LDA_FROM(A0s, 0);
  LDB_FROM(B0s, b0, 0);

  for (int t = 0; t < NT; ++t) {
    ushort_t* ldsA  = (t & 1) ? A1s : A0s;
    ushort_t* ldsB  = (t & 1) ? B1s : B0s;
    ushort_t* ldsAo = (t & 1) ? A0s : A1s;   // tile t+1's buffers
    ushort_t* ldsBo = (t & 1) ? B0s : B1s;

    // ---- PH1: q00 (A0,B0) ; then load B1(t) ; stage A1(t+1)
    LGKM0();
    if (t + 1 < NT) STAGE_A(ldsAo, Ab, t + 1, 1);
    __builtin_amdgcn_s_setprio(1);
    MFMA_QUAD(0, 0, b0);
    __builtin_amdgcn_s_setprio(0);
    SB0();
    LDB_FROM(ldsB, b1, 1);
    __builtin_amdgcn_s_barrier();

    // ---- PH2: q01 (A0,B1) ; then load A1(t) ; stage A0(t+2)
    LGKM0();
    if (t + 2 < NT) STAGE_A(ldsA, Ab, t + 2, 0);
    __builtin_amdgcn_s_setprio(1);
    MFMA_QUAD(0, 1, b1);
    __builtin_amdgcn_s_setprio(0);
    SB0();
    LDA_FROM(ldsA, 1);
    __builtin_amdgcn_s_barrier();

    // ---- PH3: q11 (A1,B1) ; stage B0(t+2) ; tile-boundary vmcnt
    LGKM0();
    if (t + 2 < NT) STAGE_B(ldsB, Bb, t + 2, 0);
    __builtin_amdgcn_s_setprio(1);
    MFMA_QUAD(1, 1, b1);
    __builtin_amdgcn_s_setprio(0);
    SB0();
    if (t + 1 < NT) {   // tile t+1 fully staged after this wait
      if (t == NT - 2) asm volatile("s_waitcnt vmcnt(0)" ::: "memory");
      else             asm volatile("s_waitcnt vmcnt(4)" ::: "memory");
    }
    __builtin_amdgcn_s_barrier();

    // ---- PH4: q10 (A1,B0) ; then load A0,B0 of t+1 ; stage B1(t+2)
    if (t + 2 < NT) STAGE_B(ldsB, Bb, t + 2, 1);
    __builtin_amdgcn_s_setprio(1);
    MFMA_QUAD(1, 0, b0);
    __builtin_amdgcn_s_setprio(0);
    SB0();
    if (t + 1 < NT) {
      LDA_FROM(ldsAo, 0);
      LDB_FROM(ldsBo, b0, 0);
    }
    __builtin_amdgcn_s_barrier();
  }

  // ---- epilogue: C write (C/D layout: row = lq*4+rr, col = l15 per 16x16 frag)
  const int r0 = lq * 4;
#pragma unroll
  for (int mf = 0; mf < 8; ++mf)
#pragma unroll
    for (int nf = 0; nf < 4; ++nf) {
      const long long base = (long long)(bm + wm + mf * 16 + r0) * N + bn + wn + nf * 16 + l15;
      if (OUT_BF16) {
        ushort_t* Cp = (ushort_t*)Cv + base;
#pragma unroll
        for (int rr = 0; rr < 4; ++rr) Cp[(long long)rr * N] = f2bf(acc[mf][nf][rr]);
      } else {
        float* Cp = (float*)Cv + base;
#pragma unroll
        for (int rr = 0; rr < 4; ++rr) Cp[(long long)rr * N] = acc[mf][nf][rr];
      }
    }
}

#undef LDA_FROM
#undef LDB_FROM
#undef MFMA_QUAD
#undef STAGE_A
#undef STAGE_B

// ---------------------------------------------------------------------------
// Fallback 128x128 GEMM (register-double-buffered) — used only if the
// dynamic-LDS attribute is unavailable.
// ---------------------------------------------------------------------------
template <bool OUT_BF16>
__launch_bounds__(256)
__global__ void gemm_bt(const ushort_t* __restrict__ A,   // [M,K] bf16
                        const ushort_t* __restrict__ Bt,  // [N,K] bf16
                        void* __restrict__ Cv, int M, int N, int K) {
  __shared__ ushort_t As[128 * 64];
  __shared__ ushort_t Bs[128 * 64];
  const int tid = threadIdx.x, lane = tid & 63, wid = tid >> 6;
  const int bm = blockIdx.y * 128, bn = blockIdx.x * 128;
  const int wm = (wid >> 1) * 64, wn = (wid & 1) * 64;

  floatx4 acc[4][4] = {};

  const int r  = tid >> 1;
  const int cp = (tid & 1) * 4;
  const int wkey = r & 7;
  const ushort_t* Ap = A  + (long long)(bm + r) * K + cp * 8;
  const ushort_t* Bp = Bt + (long long)(bn + r) * K + cp * 8;
  ushort_t* Aw = &As[r * 64];
  ushort_t* Bw = &Bs[r * 64];

  const int l15 = lane & 15, lq = lane >> 4;
  const int rkey = l15 & 7;

  bf16x8 ar[4], br[4];
#pragma unroll
  for (int i = 0; i < 4; ++i) {
    ar[i] = *(const bf16x8*)(Ap + i * 8);
    br[i] = *(const bf16x8*)(Bp + i * 8);
  }

  for (int k0 = 0; k0 < K; k0 += 64) {
    __syncthreads();
#pragma unroll
    for (int i = 0; i < 4; ++i) {
      *(bf16x8*)&Aw[((cp + i) ^ wkey) * 8] = ar[i];
      *(bf16x8*)&Bw[((cp + i) ^ wkey) * 8] = br[i];
    }
    __syncthreads();

    if (k0 + 64 < K) {
      const int kn = k0 + 64;
#pragma unroll
      for (int i = 0; i < 4; ++i) {
        ar[i] = *(const bf16x8*)(Ap + kn + i * 8);
        br[i] = *(const bf16x8*)(Bp + kn + i * 8);
      }
    }

#pragma unroll
    for (int kk = 0; kk < 2; ++kk) {
      bf16x8 af[4], bfr[4];
#pragma unroll
      for (int i = 0; i < 4; ++i) {
        af[i]  = *(const bf16x8*)&As[(wm + i * 16 + l15) * 64 + ((kk * 4 + lq) ^ rkey) * 8];
        bfr[i] = *(const bf16x8*)&Bs[(wn + i * 16 + l15) * 64 + ((kk * 4 + lq) ^ rkey) * 8];
      }
#pragma unroll
      for (int i = 0; i < 4; ++i)
#pragma unroll
        for (int j = 0; j < 4; ++j)
          acc[i][j] = __builtin_amdgcn_mfma_f32_16x16x32_bf16(af[i], bfr[j], acc[i][j], 0, 0, 0);
    }
  }

  const int r0 = lq * 4, c0 = l15;
#pragma unroll
  for (int i = 0; i < 4; ++i)
#pragma unroll
    for (int j = 0; j < 4; ++j) {
      const long long base = (long long)(bm + wm + i * 16 + r0) * N + bn + wn + j * 16 + c0;
      if (OUT_BF16) {
        ushort_t* Cp = (ushort_t*)Cv + base;
#pragma unroll
        for (int rr = 0; rr < 4; ++rr) Cp[(long long)rr * N] = f2bf(acc[i][j][rr]);
      } else {
        float* Cp = (float*)Cv + base;
#pragma unroll
        for (int rr = 0; rr < 4; ++rr) Cp[(long long)rr * N] = acc[i][j][rr];
      }
    }
}

// ---------------------------------------------------------------------------
// In-place RoPE on QKV16 [B*S][4096] bf16 (Q cols 0..2047, K cols 2048..3071).
// Also folds the 1/16 attention scale into Q. V region untouched.
// ---------------------------------------------------------------------------
__global__ void rope_inplace(ushort_t* __restrict__ QKV16, const int* __restrict__ pos) {
  const int bs  = blockIdx.x;
  const int gid = blockIdx.y * 256 + threadIdx.x;
  const int head = gid >> 7;          // 0..11
  const int d    = gid & 127;
  const float pp   = (float)pos[bs];
  const float invf = __expf(-(float)d * (9.210340371976184f / 128.0f));
  const float ang  = pp * invf;
  const float cc = cosf(ang), sn = sinf(ang);
  ushort_t* base = QKV16 + (size_t)bs * QKVW + head * HD_;
  const float x1 = bf2f(base[d]);
  const float x2 = bf2f(base[d + 128]);
  float o1 = x1 * cc - x2 * sn;
  float o2 = x2 * cc + x1 * sn;
  if (head < NH_) { o1 *= 0.0625f; o2 *= 0.0625f; }   // fold 1/sqrt(256) into Q
  base[d]       = f2bf(o1);
  base[d + 128] = f2bf(o2);
}

// ---------------------------------------------------------------------------
// V transpose: QKV16 V region -> Vt16 [B][NKV][256][S] bf16.
// ---------------------------------------------------------------------------
__global__ void v_prep(const ushort_t* __restrict__ QKV16, ushort_t* __restrict__ Vt16) {
  __shared__ ushort_t tile[32][33];
  const int k0 = blockIdx.x * 32, d0 = blockIdx.y * 32;
  const int b = blockIdx.z >> 2, hk = blockIdx.z & 3;
  const int lx = threadIdx.x & 31, ly = threadIdx.x >> 5;
#pragma unroll
  for (int i = 0; i < 4; ++i)
    tile[ly + 8 * i][lx] =
        QKV16[(size_t)(b * S_ + k0 + ly + 8 * i) * QKVW + 3072 + hk * HD_ + d0 + lx];
  __syncthreads();
#pragma unroll
  for (int i = 0; i < 4; ++i)
    Vt16[((size_t)(b * NKV_ + hk) * HD_ + d0 + ly + 8 * i) * S_ + k0 + lx] =
        tile[lx][ly + 8 * i];
}

// ---------------------------------------------------------------------------
// MFMA flash attention, head-PAIR per block (both heads share hk's K/V).
// 512 threads = 8 waves: waves 0-3 -> head 2*hp, waves 4-7 -> head 2*hp+1.
// ---------------------------------------------------------------------------
__launch_bounds__(512)
__global__ void attn_mfma(const ushort_t* __restrict__ QKV16,  // [B*S][4096]
                          const ushort_t* __restrict__ Vt16,   // [B][NKV][256][S]
                          ushort_t* __restrict__ AOb) {        // [B][S][NH][256]
  __shared__ ushort_t Ks[32 * 256];    // [key][dim], chunk-swizzled
  __shared__ ushort_t Vts[256 * 32];   // [dim][key], chunk-swizzled
  __shared__ ushort_t Ps[8][16 * 32];  // per-wave P [q][key], chunk-swizzled
  __shared__ float rsb[8][16];

  const int lane = threadIdx.x & 63, w = threadIdx.x >> 6;   // w 0..7
  const int l15 = lane & 15, lq = lane >> 4;
  const int qb = blockIdx.x * 64;
  const int hp = blockIdx.y, b = blockIdx.z;                 // hp = hk
  const int h  = hp * 2 + (w >> 2);
  const int hw = w & 3;                                      // wave-in-head

  const ushort_t* Qh = QKV16 + (size_t)b * S_ * QKVW + h * HD_;
  const ushort_t* Kh = QKV16 + (size_t)b * S_ * QKVW + 2048 + hp * HD_;
  const ushort_t* Vh = Vt16 + ((size_t)(b * NKV_ + hp) * HD_) * S_;

  const int qw = qb + hw * 16;   // wave's first query

  bf16x8 afq[8];
  {
    const ushort_t* qr = Qh + (size_t)(qw + l15) * QKVW + lq * 8;
#pragma unroll
    for (int kd = 0; kd < 8; ++kd) afq[kd] = *(const bf16x8*)(qr + kd * 32);
  }

  floatx4 acc[16] = {};
  float rs[4] = {0.f, 0.f, 0.f, 0.f};

  int kb0 = qb - (WIN_ - 1);
  if (kb0 < 0) kb0 = 0;
  kb0 &= ~31;

  const int ksp = lane & 31, ksr = lane >> 5;
  const int vsp = lane & 3,  vsr = lane >> 2;

  for (int kb = kb0; kb < qb + 64; kb += 32) {
    __syncthreads();
#pragma unroll
    for (int i = 0; i < 2; ++i) {
      const int kl = w * 4 + 2 * i + ksr;
      gl2lds16(Kh + (size_t)(kb + kl) * QKVW + (ksp ^ (kl & 31)) * 8,
               &Ks[(w * 4 + 2 * i) * 256]);
    }
#pragma unroll
    for (int i = 0; i < 2; ++i) {
      const int dl = w * 32 + 16 * i + vsr;
      gl2lds16(Vh + (size_t)dl * S_ + kb + (vsp ^ ((dl >> 1) & 3)) * 8,
               &Vts[(w * 32 + 16 * i) * 32]);
    }
    __syncthreads();

    if (kb <= qw + 15 && kb + 31 >= qw - (WIN_ - 1)) {
      ushort_t* Pw = Ps[w];
#pragma unroll
      for (int kt = 0; kt < 2; ++kt) {
        floatx4 sacc = {};
        const int keyl = kt * 16 + l15;
        const int krow = keyl * 256;
        const int ksw = keyl & 31;
#pragma unroll
        for (int kd = 0; kd < 8; ++kd) {
          bf16x8 bk = *(const bf16x8*)&Ks[krow + ((kd * 4 + lq) ^ ksw) * 8];
          sacc = __builtin_amdgcn_mfma_f32_16x16x32_bf16(afq[kd], bk, sacc, 0, 0, 0);
        }
        const int keyg = kb + keyl;
#pragma unroll
        for (int rr = 0; rr < 4; ++rr) {
          const int qg = qw + lq * 4 + rr;
          const float t = __expf(sacc[rr] * 0.04f);
          const float L = 50.f - __fdividef(100.f, t + 1.f);
          float p = __expf(L);
          p = (keyg <= qg && keyg >= qg - (WIN_ - 1)) ? p : 0.f;
          rs[rr] += p;
          const int ql = lq * 4 + rr;
          const int ch = kt * 2 + (l15 >> 3);
          Pw[ql * 32 + ((ch ^ ((ql >> 1) & 3)) * 8) + (l15 & 7)] = f2bf(p);
        }
      }
      asm volatile("s_waitcnt lgkmcnt(0)" ::: "memory");

      const bf16x8 bp = *(const bf16x8*)&Pw[l15 * 32 + ((lq ^ ((l15 >> 1) & 3)) * 8)];
      const int vsw = (l15 >> 1) & 3;
#pragma unroll
      for (int t = 0; t < 16; ++t) {
        bf16x8 av = *(const bf16x8*)&Vts[(t * 16 + l15) * 32 + ((lq ^ vsw) * 8)];
        acc[t] = __builtin_amdgcn_mfma_f32_16x16x32_bf16(av, bp, acc[t], 0, 0, 0);
      }
    }
  }

#pragma unroll
  for (int rr = 0; rr < 4; ++rr) {
    rs[rr] += __shfl_xor(rs[rr], 1, 64);
    rs[rr] += __shfl_xor(rs[rr], 2, 64);
    rs[rr] += __shfl_xor(rs[rr], 4, 64);
    rs[rr] += __shfl_xor(rs[rr], 8, 64);
  }
  if (l15 == 0) {
#pragma unroll
    for (int rr = 0; rr < 4; ++rr) rsb[w][lq * 4 + rr] = rs[rr];
  }
  asm volatile("s_waitcnt lgkmcnt(0)" ::: "memory");
  __builtin_amdgcn_wave_barrier();
  const float inv = 1.0f / rsb[w][l15];

  const size_t ob = ((size_t)(b * S_ + qw + l15) * NH_ + h) * HD_;
#pragma unroll
  for (int t = 0; t < 16; ++t) {
    ushort4 o;
    o.x = f2bf(acc[t][0] * inv);
    o.y = f2bf(acc[t][1] * inv);
    o.z = f2bf(acc[t][2] * inv);
    o.w = f2bf(acc[t][3] * inv);
    *(ushort4*)&AOb[ob + t * 16 + lq * 4] = o;
  }
}

// ---------------------------------------------------------------------------
extern "C" void kernel_launch(void* const* d_in, const int* in_sizes, int n_in,
                              void* d_out, int out_size, void* d_ws, size_t ws_size,
                              hipStream_t stream) {
  const float* X   = (const float*)d_in[0];
  const int*   pos = (const int*)d_in[2];
  const float* Wq  = (const float*)d_in[3];   // [2304, 2048]
  const float* Wk  = (const float*)d_in[4];   // [2304, 1024]
  const float* Wv  = (const float*)d_in[5];   // [2304, 1024]
  const float* Wo  = (const float*)d_in[6];   // [2048, 2304]
  float* out = (float*)d_out;

  const int M  = B_ * S_;        // 4096
  const int NQ = NH_ * HD_;      // 2048
  const int NK = NKV_ * HD_;     // 1024

  char* w = (char*)d_ws;
  ushort_t* QKV16 = (ushort_t*)w;  w += (size_t)M * QKVW * 2;          // 32 MB
  ushort_t* Xb    = (ushort_t*)w;  w += (size_t)M * H_ * 2;            // 18 MB
  ushort_t* Wqkvt = (ushort_t*)w;  w += (size_t)QKVW * H_ * 2;         // 18 MB
  ushort_t* Wot   = (ushort_t*)w;  w += (size_t)H_ * NQ * 2;           // 9.4 MB
  ushort_t* Vt16  = (ushort_t*)w;  w += (size_t)B_ * NKV_ * S_ * HD_ * 2;  // 8 MB
  ushort_t* AOb   = (ushort_t*)w;  w += (size_t)M * NQ * 2;            // 16 MB

  // opt-in to 128 KiB dynamic LDS for the pipelined GEMM (host-side, capture-safe)
  static bool g_init = false, g_8ph_ok = false;
  if (!g_init) {
    hipError_t e1 = hipFuncSetAttribute(
        reinterpret_cast<const void*>(&gemm_8ph<true>),
        hipFuncAttributeMaxDynamicSharedMemorySize, 131072);
    hipError_t e2 = hipFuncSetAttribute(
        reinterpret_cast<const void*>(&gemm_8ph<false>),
        hipFuncAttributeMaxDynamicSharedMemorySize, 131072);
    g_8ph_ok = (e1 == hipSuccess && e2 == hipSuccess);
    g_init = true;
  }

  dim3 blk(256);

  cast_bf16<<<(M * H_) / 1024, blk, 0, stream>>>(X, Xb);
  // concatenated transposed QKV weights: rows [0,2048)=Wq^T, [2048,3072)=Wk^T, [3072,4096)=Wv^T
  transpose_cast<<<dim3(NQ / 32, H_ / 32), blk, 0, stream>>>(Wq, Wqkvt, H_, NQ);
  transpose_cast<<<dim3(NK / 32, H_ / 32), blk, 0, stream>>>(Wk, Wqkvt + (size_t)2048 * H_, H_, NK);
  transpose_cast<<<dim3(NK / 32, H_ / 32), blk, 0, stream>>>(Wv, Wqkvt + (size_t)3072 * H_, H_, NK);
  transpose_cast<<<dim3(H_ / 32, NQ / 32), blk, 0, stream>>>(Wo, Wot, NQ, H_);

  // fused QKV projection, bf16 out (K=2304: 36 K-tiles; grid 16x16=256 blocks)
  if (g_8ph_ok) {
    gemm_8ph<true><<<dim3(QKVW / 256, M / 256), dim3(512), 131072, stream>>>(
        Xb, Wqkvt, QKV16, M, QKVW, H_);
  } else {
    gemm_bt<true><<<dim3(QKVW / 128, M / 128), blk, 0, stream>>>(Xb, Wqkvt, QKV16, M, QKVW, H_);
  }

  rope_inplace<<<dim3(M, 6), blk, 0, stream>>>(QKV16, pos);
  v_prep<<<dim3(S_ / 32, HD_ / 32, B_ * NKV_), blk, 0, stream>>>(QKV16, Vt16);

  // attention: head-pair per block, 512 threads
  attn_mfma<<<dim3(S_ / 64, NKV_, B_), dim3(512), 0, stream>>>(QKV16, Vt16, AOb);

  // output projection, fp32 out (K=2048: 32 K-tiles; grid 9x16=144 blocks)
  if (g_8ph_ok) {
    gemm_8ph<false><<<dim3(H_ / 256, M / 256), dim3(512), 131072, stream>>>(
        AOb, Wot, out, M, H_, NQ);
  } else {
    gemm_bt<false><<<dim3(H_ / 128, M / 128), blk, 0, stream>>>(AOb, Wot, out, M, H_, NQ);
  }
}